// Round 9
// baseline (188.631 us; speedup 1.0000x reference)
//
#include <hip/hip_runtime.h>
#include <stdint.h>

// Problem constants
constexpr int CXR = 15, ECG = 14, EHR = 13;
constexpr int TOTAL = 42;
constexpr int MPITCH = 44;          // f32 fused-matrix row pitch (fuse1 output)
constexpr float LN_EPS = 1e-5f;

// Workspace layout (float offsets)
constexpr int WS_M    = 0;                    // A_eff f32, 42 x 44
constexpr int WS_B    = TOTAL * MPITCH;       // fused bias (42)
constexpr int WS_G    = WS_B + TOTAL;         // ln gamma (42)
constexpr int WS_BETA = WS_G + TOTAL;         // ln beta  (42)
constexpr int WS_FRAG = 1976;                 // W' fp16 A-frags (16B aligned)

// Tiling: 64 rows per wave, 2 waves per block, one-shot
constexpr int WROWS = 64;
constexpr int S0F = 0, S1F = WROWS * CXR, S2F = S1F + WROWS * ECG; // 0,960,1856
constexpr int ARENA_F = S2F + WROWS * EHR;    // 2688 floats = 10752 B per wave
constexpr int WC0 = WROWS * CXR / 4, WC1 = WROWS * ECG / 4, WC2 = WROWS * EHR / 4;

typedef _Float16 half8 __attribute__((ext_vector_type(8)));
typedef float float4v __attribute__((ext_vector_type(4)));

struct FuseArgs {
    const float *in_w, *in_b, *out_w, *out_b, *kv_w, *kv_b, *ln_g, *ln_b;
    int E, R;
};

// fuse1: A_eff = out_w @ Wv @ kv_w (E x 42), b_eff, ln params -> ws (f32)
__global__ void fuse_weights_kernel(FuseArgs a0, FuseArgs a1, FuseArgs a2,
                                    float* __restrict__ ws) {
    FuseArgs a = (blockIdx.x == 0) ? a0 : (blockIdx.x == 1 ? a1 : a2);
    const int E = a.E, R = a.R;
    const int tid = threadIdx.x;

    __shared__ float T1[15 * 42];
    __shared__ float b1[15];

    for (int idx = tid; idx < E * TOTAL; idx += blockDim.x) {
        int i = idx / TOTAL, j = idx % TOTAL;
        float acc = 0.f;
        for (int k = 0; k < E; ++k)
            acc = fmaf(a.in_w[(2 * E + i) * E + k], a.kv_w[k * TOTAL + j], acc);
        T1[i * TOTAL + j] = acc;
    }
    if (tid < E) {
        float acc = a.in_b[2 * E + tid];
        for (int k = 0; k < E; ++k)
            acc = fmaf(a.in_w[(2 * E + tid) * E + k], a.kv_b[k], acc);
        b1[tid] = acc;
    }
    __syncthreads();

    for (int idx = tid; idx < E * MPITCH; idx += blockDim.x) {
        int i = idx / MPITCH, j = idx % MPITCH;
        float acc = 0.f;
        if (j < TOTAL)
            for (int k = 0; k < E; ++k)
                acc = fmaf(a.out_w[i * E + k], T1[k * TOTAL + j], acc);
        ws[WS_M + (R + i) * MPITCH + j] = acc;
    }
    if (tid < E) {
        float acc = a.out_b[tid];
        for (int k = 0; k < E; ++k)
            acc = fmaf(a.out_w[tid * E + k], b1[k], acc);
        ws[WS_B + R + tid]    = acc;
        ws[WS_G + R + tid]    = a.ln_g[tid];
        ws[WS_BETA + R + tid] = a.ln_b[tid];
    }
}

// fuse2: W' fp16 A-frags, MFMA lane order (unchanged from r8, verified).
// lane&15 = feature row within segment-m tile (pad rows ZERO);
// k = t*32 + 8*(lane>>4) + i; k==glob adds identity; k==42 is bias column.
__global__ void fuse_frags_kernel(float* __restrict__ ws) {
    const int tid = threadIdx.x;
    if (tid >= 384) return;
    const int l = tid & 63, nt = tid >> 6;   // nt = m*2 + t
    const int m = nt >> 1, t = nt & 1;
    const int j = l & 15;
    const int k0 = t * 32 + 8 * (l >> 4);
    const int offm = (m == 0) ? 0 : (m == 1 ? CXR : CXR + ECG);
    const int Em   = (m == 0) ? CXR : (m == 1 ? ECG : EHR);
    half8 h;
#pragma unroll
    for (int i = 0; i < 8; ++i) {
        int k = k0 + i;
        float v = 0.f;
        if (j < Em) {
            int glob = offm + j;
            if (k < TOTAL) {
                v = ws[WS_M + glob * MPITCH + k];
                if (k == glob) v += 1.f;          // residual identity
            } else if (k == TOTAL) {
                v = ws[WS_B + glob];              // bias via x[42]=1.0
            }
        }
        h[i] = (_Float16)v;
    }
    ((half8*)(ws + WS_FRAG))[nt * 64 + l] = h;
}

// Async global->LDS staging (linear, width 16).
template <int CH>
__device__ __forceinline__ void stage_seg(const float* __restrict__ g,
                                          float* lds_seg_base, int lane) {
#pragma unroll
    for (int it = 0; it < (CH + 63) / 64; ++it) {
        int idx = lane + it * 64;
        if (idx < CH) {
            const __attribute__((address_space(1))) void* src =
                (const __attribute__((address_space(1))) void*)
                    ((const char*)g + (size_t)idx * 16);
            __attribute__((address_space(3))) void* dst =
                (__attribute__((address_space(3))) void*)
                    ((char*)lds_seg_base + it * 1024);
            __builtin_amdgcn_global_load_lds(src, dst, 16, 0, 0);
        }
    }
}

__global__ __launch_bounds__(128) void cmca_main(
        const float* __restrict__ cxr, const float* __restrict__ ecg,
        const float* __restrict__ ehr, const float* __restrict__ ws,
        float* __restrict__ out_cxr, float* __restrict__ out_ecg,
        float* __restrict__ out_ehr) {
    __shared__ __align__(16) float sbuf[2 * ARENA_F];   // 21504 B
    const int tid = threadIdx.x;
    const int w = tid >> 6, lane = tid & 63;
    float* stg = sbuf + w * ARENA_F;
    const size_t gw = (size_t)blockIdx.x * 2 + w;
    const int h = lane >> 4, b15 = lane & 15;

    // ---- DMA stage this wave's 64-row tile ----
    stage_seg<WC0>(cxr + gw * (size_t)(WROWS * CXR), stg + S0F, lane);
    stage_seg<WC1>(ecg + gw * (size_t)(WROWS * ECG), stg + S1F, lane);
    stage_seg<WC2>(ehr + gw * (size_t)(WROWS * EHR), stg + S2F, lane);

    // ---- per-wave constants (global loads overlap the DMA) ----
    const half8* fr = (const half8*)(ws + WS_FRAG);
    half8 wf[3][2];
#pragma unroll
    for (int m = 0; m < 3; ++m)
#pragma unroll
        for (int t = 0; t < 2; ++t) wf[m][t] = fr[(m * 2 + t) * 64 + lane];

    constexpr int Earr[3] = {CXR, ECG, EHR};
    constexpr int OFFa[3] = {0, CXR, CXR + ECG};
    float gg[3][4], bb[3][4];
#pragma unroll
    for (int m = 0; m < 3; ++m)
#pragma unroll
        for (int r = 0; r < 4; ++r) {
            int j = 4 * h + r;
            bool v = j < Earr[m];
            gg[m][r] = v ? ws[WS_G + OFFa[m] + j] : 0.f;
            bb[m][r] = v ? ws[WS_BETA + OFFa[m] + j] : 0.f;
        }

    asm volatile("s_waitcnt vmcnt(0)" ::: "memory");
    __builtin_amdgcn_sched_barrier(0);

    // ---- MFMA: build B-frags (X^T) straight from staged row-major f32 ----
    // k-packing (must match fuse2): k = t2*32 + 8h + e.
    // stage float offset for feature k of batch row b:
    //   k<15 : b*15 + k ; 15<=k<29 : S1F + b*14 + (k-15) ; else S2F + b*13 + (k-29)
    const int k0a = 8 * h;
    const int k0b = 32 + 8 * h;

    float4v acc[3][4];
#pragma unroll
    for (int m = 0; m < 3; ++m)
#pragma unroll
        for (int n = 0; n < 4; ++n) acc[m][n] = float4v{0.f, 0.f, 0.f, 0.f};

#pragma unroll
    for (int n = 0; n < 4; ++n) {
        const int batch = n * 16 + b15;
        const int o15 = batch * 15;                 // seg0: + k
        const int o14 = S1F - 15 + batch * 14;      // seg1: + k
        const int o13 = S2F - 29 + batch * 13;      // seg2: + k

        half8 x0, x1;
#pragma unroll
        for (int e = 0; e < 8; ++e) {
            int k = k0a + e;                        // 0..31+e : always < 42
            int off = o15 + k;
            off = (k >= 15) ? (o14 + k) : off;
            off = (k >= 29) ? (o13 + k) : off;
            x0[e] = (_Float16)stg[off];
        }
#pragma unroll
        for (int e = 0; e < 8; ++e) {
            int k = k0b + e;                        // 32..63: seg2 / bias / zero
            float v = (k == TOTAL) ? 1.f : 0.f;
            if (k < TOTAL) v = stg[o13 + k];
            x1[e] = (_Float16)v;
        }
#pragma unroll
        for (int m = 0; m < 3; ++m) {
            acc[m][n] = __builtin_amdgcn_mfma_f32_16x16x32_f16(
                wf[m][0], x0, acc[m][n], 0, 0, 0);
            acc[m][n] = __builtin_amdgcn_mfma_f32_16x16x32_f16(
                wf[m][1], x1, acc[m][n], 0, 0, 0);
        }
    }

    // ---- in-register LN (sum/sumsq, parallel shuffle chains) + direct store ----
    // lane holds batch col = n*16+b15, features j = 4h+r of segment m.
    // Pad features are exactly 0 (zero W' rows): s and ss unaffected.
    float* const outs[3] = {
        out_cxr + gw * (size_t)(WROWS * CXR),
        out_ecg + gw * (size_t)(WROWS * ECG),
        out_ehr + gw * (size_t)(WROWS * EHR)};
#pragma unroll
    for (int m = 0; m < 3; ++m) {
        const int E = Earr[m];
        const float invE = 1.0f / E;
        float* ob = outs[m];
#pragma unroll
        for (int n = 0; n < 4; ++n) {
            float s  = acc[m][n][0] + acc[m][n][1] + acc[m][n][2] + acc[m][n][3];
            float ss = acc[m][n][0] * acc[m][n][0];
            ss = fmaf(acc[m][n][1], acc[m][n][1], ss);
            ss = fmaf(acc[m][n][2], acc[m][n][2], ss);
            ss = fmaf(acc[m][n][3], acc[m][n][3], ss);
            s  += __shfl_xor(s, 16, 64);
            ss += __shfl_xor(ss, 16, 64);
            s  += __shfl_xor(s, 32, 64);
            ss += __shfl_xor(ss, 32, 64);
            float mu  = s * invE;
            float var = fmaf(ss, invE, -mu * mu);
            float rs  = rsqrtf(var + LN_EPS);
            const int row = n * 16 + b15;
#pragma unroll
            for (int r = 0; r < 4; ++r) {
                int j = 4 * h + r;
                if (j < E) {
                    float nv = (acc[m][n][r] - mu) * rs;
                    ob[(size_t)row * E + j] = fmaf(nv, gg[m][r], bb[m][r]);
                }
            }
        }
    }
}

extern "C" void kernel_launch(void* const* d_in, const int* in_sizes, int n_in,
                              void* d_out, int out_size, void* d_ws, size_t ws_size,
                              hipStream_t stream) {
    const float* cxr = (const float*)d_in[0];
    const float* ecg = (const float*)d_in[1];
    const float* ehr = (const float*)d_in[2];
    float* ws = (float*)d_ws;
    float* out = (float*)d_out;

    const size_t Bn = (size_t)in_sizes[0] / CXR;   // 2097152

    auto mk = [&](int base, int E, int R) {
        FuseArgs a;
        a.in_w  = (const float*)d_in[base + 0];
        a.in_b  = (const float*)d_in[base + 1];
        a.out_w = (const float*)d_in[base + 2];
        a.out_b = (const float*)d_in[base + 3];
        a.kv_w  = (const float*)d_in[base + 4];
        a.kv_b  = (const float*)d_in[base + 5];
        a.ln_g  = (const float*)d_in[base + 6];
        a.ln_b  = (const float*)d_in[base + 7];
        a.E = E; a.R = R;
        return a;
    };
    FuseArgs a0 = mk(3, CXR, 0);
    FuseArgs a1 = mk(11, ECG, CXR);
    FuseArgs a2 = mk(19, EHR, CXR + ECG);

    fuse_weights_kernel<<<3, 256, 0, stream>>>(a0, a1, a2, ws);
    fuse_frags_kernel<<<1, 384, 0, stream>>>(ws);

    const int nblocks = (int)(Bn / (WROWS * 2));   // 16384 blocks x 2 waves
    cmca_main<<<nblocks, 128, 0, stream>>>(cxr, ecg, ehr, ws,
                                           out,
                                           out + Bn * CXR,
                                           out + Bn * (CXR + ECG));
}

// Round 10
// 152.221 us; speedup vs baseline: 1.2392x; 1.2392x over previous
//
#include <hip/hip_runtime.h>
#include <stdint.h>

// Problem constants
constexpr int CXR = 15, ECG = 14, EHR = 13;
constexpr int TOTAL = 42;
constexpr int MPITCH = 44;          // f32 fused-matrix row pitch (fuse1 output)
constexpr float LN_EPS = 1e-5f;

// Workspace layout (float offsets)
constexpr int WS_M    = 0;                    // A_eff f32, 42 x 44
constexpr int WS_B    = TOTAL * MPITCH;       // fused bias (42)
constexpr int WS_G    = WS_B + TOTAL;         // ln gamma (42)
constexpr int WS_BETA = WS_G + TOTAL;         // ln beta  (42)
constexpr int WS_FRAG = 1976;                 // W' fp16 A-frags (16B aligned)

// Tiling: 64 rows per wave, 2 waves per block, one-shot
constexpr int WROWS = 64;
constexpr int S0F = 0, S1F = WROWS * CXR, S2F = S1F + WROWS * ECG; // 0,960,1856
constexpr int SEG_F   = S2F + WROWS * EHR;    // 2688 floats data
constexpr int ARENA_F = SEG_F + 8;            // +8 pad: junk-tail reads stay in-bounds
constexpr int WC0 = WROWS * CXR / 4, WC1 = WROWS * ECG / 4, WC2 = WROWS * EHR / 4;

typedef _Float16 half8 __attribute__((ext_vector_type(8)));
typedef float float4v __attribute__((ext_vector_type(4)));

struct FuseArgs {
    const float *in_w, *in_b, *out_w, *out_b, *kv_w, *kv_b, *ln_g, *ln_b;
    int E, R;
};

// fuse1: A_eff = out_w @ Wv @ kv_w (E x 42), b_eff, ln params -> ws (f32)
__global__ void fuse_weights_kernel(FuseArgs a0, FuseArgs a1, FuseArgs a2,
                                    float* __restrict__ ws) {
    FuseArgs a = (blockIdx.x == 0) ? a0 : (blockIdx.x == 1 ? a1 : a2);
    const int E = a.E, R = a.R;
    const int tid = threadIdx.x;

    __shared__ float T1[15 * 42];
    __shared__ float b1[15];

    for (int idx = tid; idx < E * TOTAL; idx += blockDim.x) {
        int i = idx / TOTAL, j = idx % TOTAL;
        float acc = 0.f;
        for (int k = 0; k < E; ++k)
            acc = fmaf(a.in_w[(2 * E + i) * E + k], a.kv_w[k * TOTAL + j], acc);
        T1[i * TOTAL + j] = acc;
    }
    if (tid < E) {
        float acc = a.in_b[2 * E + tid];
        for (int k = 0; k < E; ++k)
            acc = fmaf(a.in_w[(2 * E + tid) * E + k], a.kv_b[k], acc);
        b1[tid] = acc;
    }
    __syncthreads();

    for (int idx = tid; idx < E * MPITCH; idx += blockDim.x) {
        int i = idx / MPITCH, j = idx % MPITCH;
        float acc = 0.f;
        if (j < TOTAL)
            for (int k = 0; k < E; ++k)
                acc = fmaf(a.out_w[i * E + k], T1[k * TOTAL + j], acc);
        ws[WS_M + (R + i) * MPITCH + j] = acc;
    }
    if (tid < E) {
        float acc = a.out_b[tid];
        for (int k = 0; k < E; ++k)
            acc = fmaf(a.out_w[tid * E + k], b1[k], acc);
        ws[WS_B + R + tid]    = acc;
        ws[WS_G + R + tid]    = a.ln_g[tid];
        ws[WS_BETA + R + tid] = a.ln_b[tid];
    }
}

// fuse2: W' fp16 A-frags, MFMA lane order, SEGMENT-ALIGNED k-packing:
//   pos  0-14 -> feature 0-14 (seg0);  pos 15     -> ZERO
//   pos 16-29 -> feature 15-28 (seg1); pos 30,31  -> ZERO
//   pos 32-44 -> feature 29-41 (seg2); pos 45-63  -> ZERO
// Zero positions annihilate the junk tail the B-side reads past each
// segment row. Bias is NOT in the matmul (added in epilogue).
// lane&15 = feature row within segment-m tile (pad rows ZERO);
// pos = t*32 + 8*(lane>>4) + i; identity added at feature==row.
__global__ void fuse_frags_kernel(float* __restrict__ ws) {
    const int tid = threadIdx.x;
    if (tid >= 384) return;
    const int l = tid & 63, nt = tid >> 6;   // nt = m*2 + t
    const int m = nt >> 1, t = nt & 1;
    const int j = l & 15;
    const int k0 = t * 32 + 8 * (l >> 4);
    const int offm = (m == 0) ? 0 : (m == 1 ? CXR : CXR + ECG);
    const int Em   = (m == 0) ? CXR : (m == 1 ? ECG : EHR);
    half8 h;
#pragma unroll
    for (int i = 0; i < 8; ++i) {
        int pos = k0 + i;
        int g = -1;
        if (pos < 15) g = pos;
        else if (pos >= 16 && pos < 30) g = pos - 1;
        else if (pos >= 32 && pos < 45) g = pos - 3;
        float v = 0.f;
        if (j < Em && g >= 0) {
            int gr = offm + j;
            v = ws[WS_M + gr * MPITCH + g];
            if (g == gr) v += 1.f;               // residual identity
        }
        h[i] = (_Float16)v;
    }
    ((half8*)(ws + WS_FRAG))[nt * 64 + l] = h;
}

// Async global->LDS staging (linear, width 16).
template <int CH>
__device__ __forceinline__ void stage_seg(const float* __restrict__ g,
                                          float* lds_seg_base, int lane) {
#pragma unroll
    for (int it = 0; it < (CH + 63) / 64; ++it) {
        int idx = lane + it * 64;
        if (idx < CH) {
            const __attribute__((address_space(1))) void* src =
                (const __attribute__((address_space(1))) void*)
                    ((const char*)g + (size_t)idx * 16);
            __attribute__((address_space(3))) void* dst =
                (__attribute__((address_space(3))) void*)
                    ((char*)lds_seg_base + it * 1024);
            __builtin_amdgcn_global_load_lds(src, dst, 16, 0, 0);
        }
    }
}

__global__ __launch_bounds__(128, 4) void cmca_main(
        const float* __restrict__ cxr, const float* __restrict__ ecg,
        const float* __restrict__ ehr, const float* __restrict__ ws,
        float* __restrict__ out_cxr, float* __restrict__ out_ecg,
        float* __restrict__ out_ehr) {
    __shared__ __align__(16) float sbuf[2 * ARENA_F];
    const int tid = threadIdx.x;
    const int w = tid >> 6, lane = tid & 63;
    float* stg = sbuf + w * ARENA_F;
    const size_t gw = (size_t)blockIdx.x * 2 + w;
    const int h = lane >> 4, b15 = lane & 15;

    // ---- DMA stage this wave's 64-row tile ----
    stage_seg<WC0>(cxr + gw * (size_t)(WROWS * CXR), stg + S0F, lane);
    stage_seg<WC1>(ecg + gw * (size_t)(WROWS * ECG), stg + S1F, lane);
    stage_seg<WC2>(ehr + gw * (size_t)(WROWS * EHR), stg + S2F, lane);

    // ---- W' fragments (overlap the DMA; L2-hot) ----
    const half8* fr = (const half8*)(ws + WS_FRAG);
    half8 wf[3][2];
#pragma unroll
    for (int m = 0; m < 3; ++m)
#pragma unroll
        for (int t = 0; t < 2; ++t) wf[m][t] = fr[(m * 2 + t) * 64 + lane];

    asm volatile("s_waitcnt vmcnt(0)" ::: "memory");
    __builtin_amdgcn_sched_barrier(0);

    // ---- B-frag addressing: 8 CONTIGUOUS f32 per (lane, t2) ----
    // t2=0: h=0 seg0[0:8), h=1 seg0[8:16) (1 junk), h=2 seg1[0:8),
    //       h=3 seg1[8:16) (2 junk)
    // t2=1: h=0 seg2[0:8), h=1 seg2[8:16) (3 junk), h=2,3 dummy (W'=0)
    const int e0    = (h < 2) ? 15 : 14;
    const int base0 = ((h < 2) ? S0F : S1F) + (h & 1) * 8;
    const int off1  = (h == 1) ? 8 : 0;

    float4v acc[3][4];
#pragma unroll
    for (int m = 0; m < 3; ++m)
#pragma unroll
        for (int n = 0; n < 4; ++n) acc[m][n] = float4v{0.f, 0.f, 0.f, 0.f};

#pragma unroll
    for (int n = 0; n < 4; ++n) {
        const int batch = n * 16 + b15;
        const float* p0 = stg + base0 + batch * e0;
        const float* p1 = stg + S2F + off1 + batch * 13;
        half8 x0, x1;
#pragma unroll
        for (int e = 0; e < 8; ++e) x0[e] = (_Float16)p0[e];
#pragma unroll
        for (int e = 0; e < 8; ++e) x1[e] = (_Float16)p1[e];
#pragma unroll
        for (int m = 0; m < 3; ++m) {
            acc[m][n] = __builtin_amdgcn_mfma_f32_16x16x32_f16(
                wf[m][0], x0, acc[m][n], 0, 0, 0);
            acc[m][n] = __builtin_amdgcn_mfma_f32_16x16x32_f16(
                wf[m][1], x1, acc[m][n], 0, 0, 0);
        }
    }

    // ---- epilogue: bias + in-register LN + compact LDS + coalesced store ----
    constexpr int Earr[3] = {CXR, ECG, EHR};
    constexpr int OFFa[3] = {0, CXR, CXR + ECG};
    constexpr int SEGF[3] = {S0F, S1F, S2F};
#pragma unroll
    for (int m = 0; m < 3; ++m) {
        const int E = Earr[m];
        const float invE = 1.0f / E;
        float bs[4], gm[4], bt[4];
#pragma unroll
        for (int r = 0; r < 4; ++r) {
            int j = 4 * h + r;
            bool v = j < E;
            bs[r] = v ? ws[WS_B + OFFa[m] + j] : 0.f;
            gm[r] = v ? ws[WS_G + OFFa[m] + j] : 0.f;
            bt[r] = v ? ws[WS_BETA + OFFa[m] + j] : 0.f;
        }
#pragma unroll
        for (int n = 0; n < 4; ++n) {
            float y0 = acc[m][n][0] + bs[0];
            float y1 = acc[m][n][1] + bs[1];
            float y2 = acc[m][n][2] + bs[2];
            float y3 = acc[m][n][3] + bs[3];
            float s  = (y0 + y1) + (y2 + y3);
            float ss = y0 * y0;
            ss = fmaf(y1, y1, ss);
            ss = fmaf(y2, y2, ss);
            ss = fmaf(y3, y3, ss);
            s  += __shfl_xor(s, 16, 64);
            ss += __shfl_xor(ss, 16, 64);
            s  += __shfl_xor(s, 32, 64);
            ss += __shfl_xor(ss, 32, 64);
            float mu  = s * invE;
            float var = fmaf(ss, invE, -mu * mu);
            float rs  = rsqrtf(var + LN_EPS);
            const int row = n * 16 + b15;
            float yv[4] = {y0, y1, y2, y3};
#pragma unroll
            for (int r = 0; r < 4; ++r) {
                int j = 4 * h + r;
                if (j < E)
                    stg[SEGF[m] + row * E + j] =
                        fmaf((yv[r] - mu) * rs, gm[r], bt[r]);
            }
        }
    }

    // ---- coalesced float4 stores from compact area ----
    const float4v* w4 = (const float4v*)stg;
    float4v* o0 = (float4v*)(out_cxr + gw * (size_t)(WROWS * CXR));
    float4v* o1 = (float4v*)(out_ecg + gw * (size_t)(WROWS * ECG));
    float4v* o2 = (float4v*)(out_ehr + gw * (size_t)(WROWS * EHR));
#pragma unroll
    for (int it = 0; it < 4; ++it) {
        int idx = lane + it * 64;
        if (idx < WC0) o0[idx] = w4[idx];
    }
#pragma unroll
    for (int it = 0; it < 4; ++it) {
        int idx = lane + it * 64;
        if (idx < WC1) o1[idx] = w4[WC0 + idx];
    }
#pragma unroll
    for (int it = 0; it < 4; ++it) {
        int idx = lane + it * 64;
        if (idx < WC2) o2[idx] = w4[WC0 + WC1 + idx];
    }
}

extern "C" void kernel_launch(void* const* d_in, const int* in_sizes, int n_in,
                              void* d_out, int out_size, void* d_ws, size_t ws_size,
                              hipStream_t stream) {
    const float* cxr = (const float*)d_in[0];
    const float* ecg = (const float*)d_in[1];
    const float* ehr = (const float*)d_in[2];
    float* ws = (float*)d_ws;
    float* out = (float*)d_out;

    const size_t Bn = (size_t)in_sizes[0] / CXR;   // 2097152

    auto mk = [&](int base, int E, int R) {
        FuseArgs a;
        a.in_w  = (const float*)d_in[base + 0];
        a.in_b  = (const float*)d_in[base + 1];
        a.out_w = (const float*)d_in[base + 2];
        a.out_b = (const float*)d_in[base + 3];
        a.kv_w  = (const float*)d_in[base + 4];
        a.kv_b  = (const float*)d_in[base + 5];
        a.ln_g  = (const float*)d_in[base + 6];
        a.ln_b  = (const float*)d_in[base + 7];
        a.E = E; a.R = R;
        return a;
    };
    FuseArgs a0 = mk(3, CXR, 0);
    FuseArgs a1 = mk(11, ECG, CXR);
    FuseArgs a2 = mk(19, EHR, CXR + ECG);

    fuse_weights_kernel<<<3, 256, 0, stream>>>(a0, a1, a2, ws);
    fuse_frags_kernel<<<1, 384, 0, stream>>>(ws);

    const int nblocks = (int)(Bn / (WROWS * 2));   // 16384 blocks x 2 waves
    cmca_main<<<nblocks, 128, 0, stream>>>(cxr, ecg, ehr, ws,
                                           out,
                                           out + Bn * CXR,
                                           out + Bn * (CXR + ECG));
}